// Round 1
// baseline (437.182 us; speedup 1.0000x reference)
//
#include <hip/hip_runtime.h>
#include <hip/hip_bf16.h>

#define B_ROWS 8192
#define DIM 512

typedef __bf16 bf16x8 __attribute__((ext_vector_type(8)));
typedef float f32x4 __attribute__((ext_vector_type(4)));

__device__ inline ushort f2bf(float x) {
    __hip_bfloat16 h = __float2bfloat16(x);
    return __builtin_bit_cast(ushort, h);
}

// --- Kernel 1: row-normalize A and B, cast to bf16 into workspace ---
// One wave (64 lanes) per row; each lane handles 8 consecutive floats.
__global__ __launch_bounds__(256) void norm_kernel(const float* __restrict__ A,
                                                   const float* __restrict__ Bf,
                                                   ushort* __restrict__ An,
                                                   ushort* __restrict__ Bn) {
    int gw = (blockIdx.x * 256 + threadIdx.x) >> 6;   // global wave id: 0..16383
    int lane = threadIdx.x & 63;
    const float* src;
    ushort* dst;
    if (gw < B_ROWS) {
        src = A + (size_t)gw * DIM;
        dst = An + (size_t)gw * DIM;
    } else {
        src = Bf + (size_t)(gw - B_ROWS) * DIM;
        dst = Bn + (size_t)(gw - B_ROWS) * DIM;
    }
    const float4* s4 = (const float4*)src;
    float4 v0 = s4[lane * 2];
    float4 v1 = s4[lane * 2 + 1];
    float ss = v0.x * v0.x + v0.y * v0.y + v0.z * v0.z + v0.w * v0.w
             + v1.x * v1.x + v1.y * v1.y + v1.z * v1.z + v1.w * v1.w;
#pragma unroll
    for (int m = 32; m >= 1; m >>= 1) ss += __shfl_xor(ss, m, 64);
    float scale = 1.0f / fmaxf(sqrtf(ss), 1e-8f);
    union { ushort us[8]; uint4 q; } o;
    o.us[0] = f2bf(v0.x * scale); o.us[1] = f2bf(v0.y * scale);
    o.us[2] = f2bf(v0.z * scale); o.us[3] = f2bf(v0.w * scale);
    o.us[4] = f2bf(v1.x * scale); o.us[5] = f2bf(v1.y * scale);
    o.us[6] = f2bf(v1.z * scale); o.us[7] = f2bf(v1.w * scale);
    ((uint4*)dst)[lane] = o.q;
}

// --- Kernel 2: bf16 NT-GEMM (cos = An * Bn^T), affine, store f32, fused
//     row-sum of exp(s - M) with M = |w|+|b| (bounds all scores). ---
// m97 structure: 128x128 tile, BK=32, 4 waves (2x2), global_load_lds width 16.
__global__ __launch_bounds__(256, 2) void gemm_kernel(
    const ushort* __restrict__ An, const ushort* __restrict__ Bn,
    float* __restrict__ C, float* __restrict__ row_sum,
    const float* __restrict__ wp, const float* __restrict__ bp) {
    __shared__ ushort lds[8192];  // A tile [128][32] at 0, B tile [128][32] at 4096

    const int t = threadIdx.x;
    const int brow = blockIdx.y * 128;
    const int bcol = blockIdx.x * 128;
    const int wid = t >> 6, lane = t & 63;
    const int wr = wid >> 1, wc = wid & 1;

    // staging coords: thread t loads 8 bf16 (16B); row = t>>2, col8 = (t&3)*8
    const int sr = t >> 2;
    const int sc = (t & 3) * 8;
    const ushort* gA = An + (size_t)(brow + sr) * DIM + sc;
    const ushort* gB = Bn + (size_t)(bcol + sr) * DIM + sc;
    ushort* lA = &lds[t * 8];
    ushort* lB = &lds[4096 + t * 8];

    f32x4 acc[4][4];
#pragma unroll
    for (int i = 0; i < 4; i++)
#pragma unroll
        for (int j = 0; j < 4; j++) acc[i][j] = (f32x4){0.f, 0.f, 0.f, 0.f};

    const int fr = lane & 15;        // row within 16x16 fragment
    const int fk = (lane >> 4) * 8;  // k offset within BK

    for (int kt = 0; kt < DIM / 32; ++kt) {
        const int k0 = kt * 32;
        __syncthreads();  // previous iteration's LDS reads done before overwrite
        __builtin_amdgcn_global_load_lds(
            (const __attribute__((address_space(1))) unsigned int*)(gA + k0),
            (__attribute__((address_space(3))) unsigned int*)lA, 16, 0, 0);
        __builtin_amdgcn_global_load_lds(
            (const __attribute__((address_space(1))) unsigned int*)(gA + (size_t)64 * DIM + k0),
            (__attribute__((address_space(3))) unsigned int*)(lA + 2048), 16, 0, 0);
        __builtin_amdgcn_global_load_lds(
            (const __attribute__((address_space(1))) unsigned int*)(gB + k0),
            (__attribute__((address_space(3))) unsigned int*)lB, 16, 0, 0);
        __builtin_amdgcn_global_load_lds(
            (const __attribute__((address_space(1))) unsigned int*)(gB + (size_t)64 * DIM + k0),
            (__attribute__((address_space(3))) unsigned int*)(lB + 2048), 16, 0, 0);
        __syncthreads();  // drains vmcnt (compiler emits waitcnt before barrier)

        bf16x8 af[4], bfr[4];
#pragma unroll
        for (int m = 0; m < 4; ++m) {
            int row = wr * 64 + m * 16 + fr;
            af[m] = *(const bf16x8*)&lds[row * 32 + fk];
        }
#pragma unroll
        for (int n = 0; n < 4; ++n) {
            int col = wc * 64 + n * 16 + fr;
            bfr[n] = *(const bf16x8*)&lds[4096 + col * 32 + fk];
        }
#pragma unroll
        for (int m = 0; m < 4; ++m)
#pragma unroll
            for (int n = 0; n < 4; ++n)
                acc[m][n] = __builtin_amdgcn_mfma_f32_16x16x32_bf16(af[m], bfr[n], acc[m][n], 0, 0, 0);
    }

    // Epilogue: affine, store f32 cos_score, fused row-wise sum of exp(s - M)
    const float w = wp[0], bb = bp[0];
    const float M = fabsf(w) + fabsf(bb);
#pragma unroll
    for (int m = 0; m < 4; ++m) {
#pragma unroll
        for (int r = 0; r < 4; ++r) {
            int grow = brow + wr * 64 + m * 16 + (lane >> 4) * 4 + r;
            float psum = 0.f;
#pragma unroll
            for (int n = 0; n < 4; ++n) {
                int gcol = bcol + wc * 64 + n * 16 + (lane & 15);
                float s = w * acc[m][n][r] + bb;
                C[(size_t)grow * B_ROWS + gcol] = s;
                psum += __expf(s - M);
            }
            // reduce across the 16 column-lanes (low 4 lane bits)
#pragma unroll
            for (int msk = 1; msk <= 8; msk <<= 1) psum += __shfl_xor(psum, msk, 64);
            if ((lane & 15) == 0) atomicAdd(&row_sum[grow], psum);
        }
    }
}

// --- Kernel 3: loss = -mean(diag(s) - M - log(row_sum)) ---
__global__ __launch_bounds__(1024) void loss_kernel(const float* __restrict__ C,
                                                    const float* __restrict__ row_sum,
                                                    const float* __restrict__ wp,
                                                    const float* __restrict__ bp,
                                                    float* __restrict__ out0) {
    __shared__ float sred[16];
    float M = fabsf(wp[0]) + fabsf(bp[0]);
    float local = 0.f;
    for (int i = threadIdx.x; i < B_ROWS; i += 1024) {
        float sii = C[(size_t)i * (B_ROWS + 1)];
        local += sii - M - __logf(row_sum[i]);
    }
#pragma unroll
    for (int m = 32; m >= 1; m >>= 1) local += __shfl_xor(local, m, 64);
    if ((threadIdx.x & 63) == 0) sred[threadIdx.x >> 6] = local;
    __syncthreads();
    if (threadIdx.x == 0) {
        float tot = 0.f;
        for (int i = 0; i < 16; ++i) tot += sred[i];
        out0[0] = -tot / (float)B_ROWS;
    }
}

extern "C" void kernel_launch(void* const* d_in, const int* in_sizes, int n_in,
                              void* d_out, int out_size, void* d_ws, size_t ws_size,
                              hipStream_t stream) {
    // inputs: 0=label (unused, labels are arange), 1=feature_a, 2=feature_b,
    //         3=affine_w, 4=affine_b
    const float* A  = (const float*)d_in[1];
    const float* Bf = (const float*)d_in[2];
    const float* wp = (const float*)d_in[3];
    const float* bp = (const float*)d_in[4];
    float* out = (float*)d_out;  // [0] = loss, [1..] = cos_score row-major

    ushort* An = (ushort*)d_ws;
    ushort* Bn = An + (size_t)B_ROWS * DIM;
    float* row_sum = (float*)((char*)d_ws + (size_t)2 * B_ROWS * DIM * sizeof(ushort));

    hipMemsetAsync(row_sum, 0, B_ROWS * sizeof(float), stream);
    norm_kernel<<<dim3(16384 * 64 / 256), 256, 0, stream>>>(A, Bf, An, Bn);
    dim3 grid(B_ROWS / 128, B_ROWS / 128);
    gemm_kernel<<<grid, 256, 0, stream>>>(An, Bn, out + 1, row_sum, wp, bp);
    loss_kernel<<<1, 1024, 0, stream>>>(out + 1, row_sum, wp, bp, out);
}

// Round 2
// 397.687 us; speedup vs baseline: 1.0993x; 1.0993x over previous
//
#include <hip/hip_runtime.h>
#include <hip/hip_bf16.h>

#define B_ROWS 8192
#define DIM 512

typedef __bf16 bf16x8 __attribute__((ext_vector_type(8)));
typedef float f32x4 __attribute__((ext_vector_type(4)));

__device__ inline ushort f2bf(float x) {
    __hip_bfloat16 h = __float2bfloat16(x);
    return __builtin_bit_cast(ushort, h);
}

// --- Kernel 1: row-normalize A and B, cast to bf16 into workspace ---
__global__ __launch_bounds__(256) void norm_kernel(const float* __restrict__ A,
                                                   const float* __restrict__ Bf,
                                                   ushort* __restrict__ An,
                                                   ushort* __restrict__ Bn) {
    int gw = (blockIdx.x * 256 + threadIdx.x) >> 6;   // 0..16383
    int lane = threadIdx.x & 63;
    const float* src;
    ushort* dst;
    if (gw < B_ROWS) {
        src = A + (size_t)gw * DIM;
        dst = An + (size_t)gw * DIM;
    } else {
        src = Bf + (size_t)(gw - B_ROWS) * DIM;
        dst = Bn + (size_t)(gw - B_ROWS) * DIM;
    }
    const float4* s4 = (const float4*)src;
    float4 v0 = s4[lane * 2];
    float4 v1 = s4[lane * 2 + 1];
    float ss = v0.x * v0.x + v0.y * v0.y + v0.z * v0.z + v0.w * v0.w
             + v1.x * v1.x + v1.y * v1.y + v1.z * v1.z + v1.w * v1.w;
#pragma unroll
    for (int m = 32; m >= 1; m >>= 1) ss += __shfl_xor(ss, m, 64);
    float scale = 1.0f / fmaxf(sqrtf(ss), 1e-8f);
    union { ushort us[8]; uint4 q; } o;
    o.us[0] = f2bf(v0.x * scale); o.us[1] = f2bf(v0.y * scale);
    o.us[2] = f2bf(v0.z * scale); o.us[3] = f2bf(v0.w * scale);
    o.us[4] = f2bf(v1.x * scale); o.us[5] = f2bf(v1.y * scale);
    o.us[6] = f2bf(v1.z * scale); o.us[7] = f2bf(v1.w * scale);
    ((uint4*)dst)[lane] = o.q;
}

// --- Kernel 2: 256x256-tile bf16 NT-GEMM, 2-phase double-buffered,
//     swizzled LDS (pre-swizzled global source), fused affine+exp rowsum. ---
#define GLDS(src, dst) __builtin_amdgcn_global_load_lds( \
    (const __attribute__((address_space(1))) unsigned int*)(src), \
    (__attribute__((address_space(3))) unsigned int*)(dst), 16, 0, 0)

__global__ __launch_bounds__(512, 2) void gemm_kernel(
    const ushort* __restrict__ An, const ushort* __restrict__ Bn,
    float* __restrict__ C, float* __restrict__ rowpart,
    const float* __restrict__ wp, const float* __restrict__ bp) {
    // Per buffer: [256 rows][32 k] bf16 = 16 KB. A + B, double-buffered = 64 KB.
    __shared__ ushort ldsA[2][8192];
    __shared__ ushort ldsB[2][8192];

    const int t = threadIdx.x;
    const int brow = blockIdx.y * 256;
    const int bcol = blockIdx.x * 256;
    const int wid = t >> 6, lane = t & 63;
    const int wr = wid >> 2, wc = wid & 3;      // 2 x 4 wave grid
    const int fr = lane & 15;
    const int fhi = lane >> 4;                  // 0..3 = k-chunk index

    // Staging: thread t fetches 16B for LDS (row = j*128 + t>>2, chunk = t&3).
    // Swizzle (both-sides): LDS(row,c) holds global chunk c ^ ((row>>1)&3).
    const int srow = t >> 2;
    const int schunk = (t & 3) ^ ((t >> 3) & 3);   // (row>>1)&3 == (t>>3)&3
    const ushort* gA0 = An + (size_t)(brow + srow) * DIM + schunk * 8;
    const ushort* gA1 = gA0 + (size_t)128 * DIM;
    const ushort* gB0 = Bn + (size_t)(bcol + srow) * DIM + schunk * 8;
    const ushort* gB1 = gB0 + (size_t)128 * DIM;

#define STAGE(buf, kt) do { const int k0_ = (kt) * 32;            \
        GLDS(gA0 + k0_, &ldsA[buf][t * 8]);                       \
        GLDS(gA1 + k0_, &ldsA[buf][4096 + t * 8]);                \
        GLDS(gB0 + k0_, &ldsB[buf][t * 8]);                       \
        GLDS(gB1 + k0_, &ldsB[buf][4096 + t * 8]); } while (0)

    f32x4 acc[8][4];
#pragma unroll
    for (int i = 0; i < 8; i++)
#pragma unroll
        for (int j = 0; j < 4; j++) acc[i][j] = (f32x4){0.f, 0.f, 0.f, 0.f};

    // Read addressing: want global chunk = fhi at row; stored at chunk fhi ^ ((row>>1)&3).
    // For A rows (wr*128 + m*16 + fr) and B rows (wc*64 + n*16 + fr): (row>>1)&3 == (fr>>1)&3.
    const int rchunk = (fhi ^ ((fr >> 1) & 3)) * 8;

    STAGE(0, 0);
    __syncthreads();   // compiler drains vmcnt before barrier

    int cur = 0;
#pragma unroll
    for (int kt = 0; kt < 16; ++kt) {
        if (kt < 15) STAGE(cur ^ 1, kt + 1);   // prefetch next K-tile (in flight)
        bf16x8 af[8], bfr[4];
#pragma unroll
        for (int m = 0; m < 8; ++m)
            af[m] = *(const bf16x8*)&ldsA[cur][(wr * 128 + m * 16 + fr) * 32 + rchunk];
#pragma unroll
        for (int n = 0; n < 4; ++n)
            bfr[n] = *(const bf16x8*)&ldsB[cur][(wc * 64 + n * 16 + fr) * 32 + rchunk];
        __builtin_amdgcn_s_setprio(1);
#pragma unroll
        for (int m = 0; m < 8; ++m)
#pragma unroll
            for (int n = 0; n < 4; ++n)
                acc[m][n] = __builtin_amdgcn_mfma_f32_16x16x32_bf16(af[m], bfr[n], acc[m][n], 0, 0, 0);
        __builtin_amdgcn_s_setprio(0);
        __syncthreads();   // vmcnt(0)+lgkmcnt(0) drain: next buffer staged, reads done
        cur ^= 1;
    }

    // Epilogue: affine, f32 store, row-wise sum of exp(s - M), M = |w|+|b| >= all s.
    const float w = wp[0], bb = bp[0];
    const float M = fabsf(w) + fabsf(bb);
    float* part = (float*)&ldsA[0][0];   // reuse LDS: [4 col-waves][256 rows]
#pragma unroll
    for (int m = 0; m < 8; ++m) {
#pragma unroll
        for (int r = 0; r < 4; ++r) {
            const int rloc = wr * 128 + m * 16 + fhi * 4 + r;
            const size_t grow = (size_t)(brow + rloc);
            float psum = 0.f;
#pragma unroll
            for (int n = 0; n < 4; ++n) {
                const int gcol = bcol + wc * 64 + n * 16 + fr;
                float s = fmaf(w, acc[m][n][r], bb);
                C[grow * B_ROWS + gcol] = s;
                psum += __expf(s - M);
            }
#pragma unroll
            for (int msk = 1; msk <= 8; msk <<= 1) psum += __shfl_xor(psum, msk, 64);
            if (fr == 0) part[wc * 256 + rloc] = psum;
        }
    }
    __syncthreads();
    if (t < 256) {
        float s = part[t] + part[256 + t] + part[512 + t] + part[768 + t];
        rowpart[(size_t)blockIdx.x * B_ROWS + brow + t] = s;
    }
#undef STAGE
}

// --- Kernel 3: loss = -mean(diag(s) - M - log(rowsum)) ---
__global__ __launch_bounds__(256) void loss_kernel(const float* __restrict__ C,
                                                   const float* __restrict__ rowpart,
                                                   const float* __restrict__ wp,
                                                   const float* __restrict__ bp,
                                                   float* __restrict__ out0) {
    __shared__ float sred[4];
    const int row = blockIdx.x * 256 + threadIdx.x;
    float rs = 0.f;
#pragma unroll
    for (int j = 0; j < 32; ++j) rs += rowpart[(size_t)j * B_ROWS + row];
    const float M = fabsf(wp[0]) + fabsf(bp[0]);
    const float sii = C[(size_t)row * B_ROWS + row];
    float v = sii - M - __logf(rs);
#pragma unroll
    for (int msk = 32; msk >= 1; msk >>= 1) v += __shfl_xor(v, msk, 64);
    if ((threadIdx.x & 63) == 0) sred[threadIdx.x >> 6] = v;
    __syncthreads();
    if (threadIdx.x == 0) {
        float tot = sred[0] + sred[1] + sred[2] + sred[3];
        atomicAdd(out0, -tot / (float)B_ROWS);
    }
}

extern "C" void kernel_launch(void* const* d_in, const int* in_sizes, int n_in,
                              void* d_out, int out_size, void* d_ws, size_t ws_size,
                              hipStream_t stream) {
    const float* A  = (const float*)d_in[1];
    const float* Bf = (const float*)d_in[2];
    const float* wp = (const float*)d_in[3];
    const float* bp = (const float*)d_in[4];
    float* out = (float*)d_out;  // [0] = loss, [1..] = cos_score row-major

    ushort* An = (ushort*)d_ws;
    ushort* Bn = An + (size_t)B_ROWS * DIM;
    float* rowpart = (float*)((char*)d_ws + (size_t)2 * B_ROWS * DIM * sizeof(ushort));

    hipMemsetAsync(d_out, 0, sizeof(float), stream);  // zero the loss slot
    norm_kernel<<<dim3(16384 * 64 / 256), 256, 0, stream>>>(A, Bf, An, Bn);
    dim3 grid(B_ROWS / 256, B_ROWS / 256);
    gemm_kernel<<<grid, 512, 0, stream>>>(An, Bn, out + 1, rowpart, wp, bp);
    loss_kernel<<<B_ROWS / 256, 256, 0, stream>>>(out + 1, rowpart, wp, bp, out);
}

// Round 3
// 391.676 us; speedup vs baseline: 1.1162x; 1.0153x over previous
//
#include <hip/hip_runtime.h>
#include <hip/hip_bf16.h>

#define B_ROWS 8192
#define DIM 512

typedef __bf16 bf16x8 __attribute__((ext_vector_type(8)));
typedef float f32x4 __attribute__((ext_vector_type(4)));

__device__ inline ushort f2bf(float x) {
    __hip_bfloat16 h = __float2bfloat16(x);
    return __builtin_bit_cast(ushort, h);
}

// --- Kernel 1: row-normalize A and B, cast to bf16 into workspace ---
__global__ __launch_bounds__(256) void norm_kernel(const float* __restrict__ A,
                                                   const float* __restrict__ Bf,
                                                   ushort* __restrict__ An,
                                                   ushort* __restrict__ Bn) {
    int gw = (blockIdx.x * 256 + threadIdx.x) >> 6;   // 0..16383
    int lane = threadIdx.x & 63;
    const float* src;
    ushort* dst;
    if (gw < B_ROWS) {
        src = A + (size_t)gw * DIM;
        dst = An + (size_t)gw * DIM;
    } else {
        src = Bf + (size_t)(gw - B_ROWS) * DIM;
        dst = Bn + (size_t)(gw - B_ROWS) * DIM;
    }
    const float4* s4 = (const float4*)src;
    float4 v0 = s4[lane * 2];
    float4 v1 = s4[lane * 2 + 1];
    float ss = v0.x * v0.x + v0.y * v0.y + v0.z * v0.z + v0.w * v0.w
             + v1.x * v1.x + v1.y * v1.y + v1.z * v1.z + v1.w * v1.w;
#pragma unroll
    for (int m = 32; m >= 1; m >>= 1) ss += __shfl_xor(ss, m, 64);
    float scale = 1.0f / fmaxf(sqrtf(ss), 1e-8f);
    union { ushort us[8]; uint4 q; } o;
    o.us[0] = f2bf(v0.x * scale); o.us[1] = f2bf(v0.y * scale);
    o.us[2] = f2bf(v0.z * scale); o.us[3] = f2bf(v0.w * scale);
    o.us[4] = f2bf(v1.x * scale); o.us[5] = f2bf(v1.y * scale);
    o.us[6] = f2bf(v1.z * scale); o.us[7] = f2bf(v1.w * scale);
    ((uint4*)dst)[lane] = o.q;
}

// --- Kernel 2: 256x256-tile bf16 NT-GEMM, TRIPLE-buffered (stage t+2 while
//     computing t), counted vmcnt(4) + raw s_barrier per iter (no full drain),
//     swizzled LDS, fused affine + exp row-sum epilogue. ---
#define GLDS(src, dst) __builtin_amdgcn_global_load_lds( \
    (const __attribute__((address_space(1))) unsigned int*)(src), \
    (__attribute__((address_space(3))) unsigned int*)(dst), 16, 0, 0)

__global__ __launch_bounds__(512, 2) void gemm_kernel(
    const ushort* __restrict__ An, const ushort* __restrict__ Bn,
    float* __restrict__ C, float* __restrict__ rowpart,
    const float* __restrict__ wp, const float* __restrict__ bp) {
    // Per buffer: [256 rows][32 k] bf16 = 16 KB. A + B, triple-buffered = 96 KB.
    __shared__ ushort ldsA[3][8192];
    __shared__ ushort ldsB[3][8192];

    const int t = threadIdx.x;
    const int brow = blockIdx.y * 256;
    const int bcol = blockIdx.x * 256;
    const int wid = t >> 6, lane = t & 63;
    const int wr = wid >> 2, wc = wid & 3;      // 2 x 4 wave grid
    const int fr = lane & 15;
    const int fhi = lane >> 4;                  // 0..3 = k-chunk index

    // Staging: thread t fetches 16B (row = t>>2, chunk = t&3), swizzled source:
    // LDS(row,c) holds global chunk c ^ ((row>>1)&3).
    const int srow = t >> 2;
    const int schunk = (t & 3) ^ ((t >> 3) & 3);
    const ushort* gA0 = An + (size_t)(brow + srow) * DIM + schunk * 8;
    const ushort* gA1 = gA0 + (size_t)128 * DIM;
    const ushort* gB0 = Bn + (size_t)(bcol + srow) * DIM + schunk * 8;
    const ushort* gB1 = gB0 + (size_t)128 * DIM;

#define STAGE(buf, kt) do { const int k0_ = (kt) * 32;            \
        GLDS(gA0 + k0_, &ldsA[buf][t * 8]);                       \
        GLDS(gA1 + k0_, &ldsA[buf][4096 + t * 8]);                \
        GLDS(gB0 + k0_, &ldsB[buf][t * 8]);                       \
        GLDS(gB1 + k0_, &ldsB[buf][4096 + t * 8]); } while (0)

    f32x4 acc[8][4];
#pragma unroll
    for (int i = 0; i < 8; i++)
#pragma unroll
        for (int j = 0; j < 4; j++) acc[i][j] = (f32x4){0.f, 0.f, 0.f, 0.f};

    // Read addressing: global chunk fhi at row r lives at chunk fhi ^ ((r>>1)&3);
    // for rows m*16+fr (any m), (r>>1)&3 == (fr>>1)&3.
    const int rchunk = (fhi ^ ((fr >> 1) & 3)) * 8;

    // Prologue: stage K-tiles 0 and 1; wait for 0 (4 loads of tile 1 in flight).
    STAGE(0, 0);
    STAGE(1, 1);
    asm volatile("s_waitcnt vmcnt(4)\n\ts_barrier" ::: "memory");

#pragma unroll
    for (int kt = 0; kt < 16; ++kt) {
        if (kt + 2 < 16) STAGE((kt + 2) % 3, kt + 2);  // lands 2 iters from now
        const int cb = kt % 3;
        bf16x8 af[8], bfr[4];
#pragma unroll
        for (int m = 0; m < 8; ++m)
            af[m] = *(const bf16x8*)&ldsA[cb][(wr * 128 + m * 16 + fr) * 32 + rchunk];
#pragma unroll
        for (int n = 0; n < 4; ++n)
            bfr[n] = *(const bf16x8*)&ldsB[cb][(wc * 64 + n * 16 + fr) * 32 + rchunk];
        __builtin_amdgcn_s_setprio(1);
#pragma unroll
        for (int m = 0; m < 8; ++m)
#pragma unroll
            for (int n = 0; n < 4; ++n)
                acc[m][n] = __builtin_amdgcn_mfma_f32_16x16x32_bf16(af[m], bfr[n], acc[m][n], 0, 0, 0);
        __builtin_amdgcn_s_setprio(0);
        // End-of-iter: wait for NEXT buffer's stage (issued 2 iters ago ->
        // counted wait is ~free), then raw barrier (no lgkm/vm full drain).
        if (kt <= 13) {
            asm volatile("s_waitcnt vmcnt(4)\n\ts_barrier" ::: "memory");
        } else if (kt == 14) {
            asm volatile("s_waitcnt vmcnt(0)\n\ts_barrier" ::: "memory");
        }
        // kt == 15: epilogue's __syncthreads() provides the final barrier.
    }

    // Epilogue: affine, f32 store, row-wise sum of exp(s - M), M = |w|+|b| >= s.
    __syncthreads();   // all waves done reading LDS before reuse as partials
    const float w = wp[0], bb = bp[0];
    const float M = fabsf(w) + fabsf(bb);
    float* part = (float*)&ldsA[0][0];   // [4 col-waves][256 rows]
#pragma unroll
    for (int m = 0; m < 8; ++m) {
#pragma unroll
        for (int r = 0; r < 4; ++r) {
            const int rloc = wr * 128 + m * 16 + fhi * 4 + r;
            const size_t grow = (size_t)(brow + rloc);
            float psum = 0.f;
#pragma unroll
            for (int n = 0; n < 4; ++n) {
                const int gcol = bcol + wc * 64 + n * 16 + fr;
                float s = fmaf(w, acc[m][n][r], bb);
                C[grow * B_ROWS + gcol] = s;
                psum += __expf(s - M);
            }
#pragma unroll
            for (int msk = 1; msk <= 8; msk <<= 1) psum += __shfl_xor(psum, msk, 64);
            if (fr == 0) part[wc * 256 + rloc] = psum;
        }
    }
    __syncthreads();
    if (t < 256) {
        float s = part[t] + part[256 + t] + part[512 + t] + part[768 + t];
        rowpart[(size_t)blockIdx.x * B_ROWS + brow + t] = s;
    }
#undef STAGE
}

// --- Kernel 3: loss = -mean(diag(s) - M - log(rowsum)) ---
__global__ __launch_bounds__(256) void loss_kernel(const float* __restrict__ C,
                                                   const float* __restrict__ rowpart,
                                                   const float* __restrict__ wp,
                                                   const float* __restrict__ bp,
                                                   float* __restrict__ out0) {
    __shared__ float sred[4];
    const int row = blockIdx.x * 256 + threadIdx.x;
    float rs = 0.f;
#pragma unroll
    for (int j = 0; j < 32; ++j) rs += rowpart[(size_t)j * B_ROWS + row];
    const float M = fabsf(wp[0]) + fabsf(bp[0]);
    const float sii = C[(size_t)row * B_ROWS + row];
    float v = sii - M - __logf(rs);
#pragma unroll
    for (int msk = 32; msk >= 1; msk >>= 1) v += __shfl_xor(v, msk, 64);
    if ((threadIdx.x & 63) == 0) sred[threadIdx.x >> 6] = v;
    __syncthreads();
    if (threadIdx.x == 0) {
        float tot = sred[0] + sred[1] + sred[2] + sred[3];
        atomicAdd(out0, -tot / (float)B_ROWS);
    }
}

extern "C" void kernel_launch(void* const* d_in, const int* in_sizes, int n_in,
                              void* d_out, int out_size, void* d_ws, size_t ws_size,
                              hipStream_t stream) {
    const float* A  = (const float*)d_in[1];
    const float* Bf = (const float*)d_in[2];
    const float* wp = (const float*)d_in[3];
    const float* bp = (const float*)d_in[4];
    float* out = (float*)d_out;  // [0] = loss, [1..] = cos_score row-major

    ushort* An = (ushort*)d_ws;
    ushort* Bn = An + (size_t)B_ROWS * DIM;
    float* rowpart = (float*)((char*)d_ws + (size_t)2 * B_ROWS * DIM * sizeof(ushort));

    hipMemsetAsync(d_out, 0, sizeof(float), stream);  // zero the loss slot
    norm_kernel<<<dim3(16384 * 64 / 256), 256, 0, stream>>>(A, Bf, An, Bn);
    dim3 grid(B_ROWS / 256, B_ROWS / 256);
    gemm_kernel<<<grid, 512, 0, stream>>>(An, Bn, out + 1, rowpart, wp, bp);
    loss_kernel<<<B_ROWS / 256, 256, 0, stream>>>(out + 1, rowpart, wp, bp, out);
}

// Round 7
// 387.653 us; speedup vs baseline: 1.1278x; 1.0104x over previous
//
#include <hip/hip_runtime.h>
#include <hip/hip_bf16.h>

#define B_ROWS 8192
#define DIM 512

typedef __bf16 bf16x8 __attribute__((ext_vector_type(8)));
typedef float f32x4 __attribute__((ext_vector_type(4)));

__device__ inline ushort f2bf(float x) {
    __hip_bfloat16 h = __float2bfloat16(x);
    return __builtin_bit_cast(ushort, h);
}

// --- Kernel 1: row-normalize A and B, cast to bf16 into workspace ---
__global__ __launch_bounds__(256) void norm_kernel(const float* __restrict__ A,
                                                   const float* __restrict__ Bf,
                                                   ushort* __restrict__ An,
                                                   ushort* __restrict__ Bn) {
    int gw = (blockIdx.x * 256 + threadIdx.x) >> 6;   // 0..16383
    int lane = threadIdx.x & 63;
    const float* src;
    ushort* dst;
    if (gw < B_ROWS) {
        src = A + (size_t)gw * DIM;
        dst = An + (size_t)gw * DIM;
    } else {
        src = Bf + (size_t)(gw - B_ROWS) * DIM;
        dst = Bn + (size_t)(gw - B_ROWS) * DIM;
    }
    const float4* s4 = (const float4*)src;
    float4 v0 = s4[lane * 2];
    float4 v1 = s4[lane * 2 + 1];
    float ss = v0.x * v0.x + v0.y * v0.y + v0.z * v0.z + v0.w * v0.w
             + v1.x * v1.x + v1.y * v1.y + v1.z * v1.z + v1.w * v1.w;
#pragma unroll
    for (int m = 32; m >= 1; m >>= 1) ss += __shfl_xor(ss, m, 64);
    float scale = 1.0f / fmaxf(sqrtf(ss), 1e-8f);
    union { ushort us[8]; uint4 q; } o;
    o.us[0] = f2bf(v0.x * scale); o.us[1] = f2bf(v0.y * scale);
    o.us[2] = f2bf(v0.z * scale); o.us[3] = f2bf(v0.w * scale);
    o.us[4] = f2bf(v1.x * scale); o.us[5] = f2bf(v1.y * scale);
    o.us[6] = f2bf(v1.z * scale); o.us[7] = f2bf(v1.w * scale);
    ((uint4*)dst)[lane] = o.q;
}

// --- Kernel 2: 256x256-tile bf16 NT-GEMM, 8-phase schedule (4 phases/K-tile,
//     BK=64, double-buffered 128KB LDS, counted vmcnt, setprio), fused
//     affine + exp row-sum epilogue. ---
#define GLDS(src, dst) __builtin_amdgcn_global_load_lds( \
    (const __attribute__((address_space(1))) unsigned int*)(src), \
    (__attribute__((address_space(3))) unsigned int*)(dst), 16, 0, 0)

// Stage one half-tile (both kk sub-tiles) of matrix `ab` into buffer `bufv`.
#define STG(bufv, ab, PTR, doff, ktv) do {                                   \
    GLDS((PTR) + (ktv) * 64,      L + (((bufv)*2 + (ab))*2 + 0)*8192 + (doff)); \
    GLDS((PTR) + (ktv) * 64 + 32, L + (((bufv)*2 + (ab))*2 + 1)*8192 + (doff)); } while (0)

#define BARRIER() asm volatile("s_barrier" ::: "memory")

__global__ __launch_bounds__(512, 2) void gemm_kernel(
    const ushort* __restrict__ An, const ushort* __restrict__ Bn,
    float* __restrict__ C, float* __restrict__ rowpart,
    const float* __restrict__ wp, const float* __restrict__ bp) {
    // [buf][A,B][kkhalf][256 rows * 32 k] bf16 = 128 KB total.
    __shared__ ushort lds[2][2][2][8192];
    ushort* L = &lds[0][0][0][0];

    const int t = threadIdx.x;
    const int brow = blockIdx.y * 256;
    const int bcol = blockIdx.x * 256;
    const int wid = t >> 6, lane = t & 63;
    const int wr = wid >> 2, wc = wid & 3;   // 2 x 4 wave grid, wave tile 128x64
    const int fr = lane & 15;
    const int fhi = lane >> 4;

    // ---- staging addressing (quadrant-matched halves, per-wave-linear) ----
    // A-halfA: rows 0-63 & 128-191 (m0-3 rows for both wr); A-halfB: +64.
    // B-halfA: rows r with (r>>5)&1==0 (n0-1 cols for all wc); B-halfB: +32.
    const int schunk8 = ((t & 3) ^ ((t >> 3) & 3)) * 8;  // source chunk (swizzle)
    const int srowAa = (t >> 8) * 128 + ((t >> 2) & 63);
    const int srowBa = (t >> 7) * 64 + ((t >> 2) & 31);
    const ushort* pAa = An + (size_t)(brow + srowAa) * DIM + schunk8;
    const ushort* pAb = An + (size_t)(brow + srowAa + 64) * DIM + schunk8;
    const ushort* pBa = Bn + (size_t)(bcol + srowBa) * DIM + schunk8;
    const ushort* pBb = Bn + (size_t)(bcol + srowBa + 32) * DIM + schunk8;
    // LDS dest offsets (ushorts) within a [256][32] sub-tile:
    const int dAa = t * 8 + (t >> 8) * 2048;  // row*32 + (t&3)*8
    const int dAb = dAa + 2048;               // +64 rows
    const int dBa = t * 8 + (t >> 7) * 1024;
    const int dBb = dBa + 1024;               // +32 rows

    // ---- fragment read addressing ----
    // stored chunk c holds global chunk c ^ ((row>>1)&3); rows = *+16m+fr so
    // (row>>1)&3 == (fr>>1)&3 always.
    const int rchunk8 = (fhi ^ ((fr >> 1) & 3)) * 8;

    f32x4 acc[8][4];
#pragma unroll
    for (int i = 0; i < 8; i++)
#pragma unroll
        for (int j = 0; j < 4; j++) acc[i][j] = (f32x4){0.f, 0.f, 0.f, 0.f};

    bf16x8 af[4][2], b0[2][2], b1[2][2];

    auto rdA = [&](int buf, int mb) {
#pragma unroll
        for (int i = 0; i < 4; ++i)
#pragma unroll
            for (int kk = 0; kk < 2; ++kk)
                af[i][kk] = *(const bf16x8*)(L + ((buf * 2 + 0) * 2 + kk) * 8192
                            + (wr * 128 + (mb + i) * 16 + fr) * 32 + rchunk8);
    };
    auto rdB = [&](bf16x8 (&b)[2][2], int buf, int nb) {
#pragma unroll
        for (int j = 0; j < 2; ++j)
#pragma unroll
            for (int kk = 0; kk < 2; ++kk)
                b[j][kk] = *(const bf16x8*)(L + ((buf * 2 + 1) * 2 + kk) * 8192
                           + (wc * 64 + (nb + j) * 16 + fr) * 32 + rchunk8);
    };
    auto mfma16 = [&](bf16x8 (&b)[2][2], int mb, int nb) {
        __builtin_amdgcn_sched_barrier(0);
        __builtin_amdgcn_s_setprio(1);
#pragma unroll
        for (int i = 0; i < 4; ++i)
#pragma unroll
            for (int j = 0; j < 2; ++j)
#pragma unroll
                for (int kk = 0; kk < 2; ++kk)
                    acc[mb + i][nb + j] = __builtin_amdgcn_mfma_f32_16x16x32_bf16(
                        af[i][kk], b[j][kk], acc[mb + i][nb + j], 0, 0, 0);
        __builtin_amdgcn_s_setprio(0);
        __builtin_amdgcn_sched_barrier(0);
    };

    // ---- prologue: stage K-tile 0 fully, full drain ----
    STG(0, 0, pAa, dAa, 0);
    STG(0, 1, pBa, dBa, 0);
    STG(0, 0, pAb, dAb, 0);
    STG(0, 1, pBb, dBb, 0);
    asm volatile("s_waitcnt vmcnt(0)\n\ts_barrier" ::: "memory");

#pragma unroll
    for (int kt = 0; kt < 8; ++kt) {
        const int cur = kt & 1, nxt = cur ^ 1;
        // ---- P1: quadrant m0-3 x n0-1 ----
        if (kt < 7) STG(nxt, 0, pAa, dAa, kt + 1);
        rdA(cur, 0);
        rdB(b0, cur, 0);
        BARRIER();
        mfma16(b0, 0, 0);
        if (kt == 7) { asm volatile("s_waitcnt vmcnt(0)\n\ts_barrier" ::: "memory"); }
        else         { asm volatile("s_waitcnt vmcnt(2)\n\ts_barrier" ::: "memory"); }
        // ---- P2: m0-3 x n2-3 ----
        if (kt < 7) STG(nxt, 1, pBa, dBa, kt + 1);
        rdB(b1, cur, 2);
        BARRIER();
        mfma16(b1, 0, 2);
        BARRIER();
        // ---- P3: m4-7 x n2-3 ----
        if (kt < 7) STG(nxt, 0, pAb, dAb, kt + 1);
        rdA(cur, 4);
        BARRIER();
        mfma16(b1, 4, 2);
        BARRIER();
        // ---- P4: m4-7 x n0-1 (b0 held from P1) ----
        if (kt < 7) STG(nxt, 1, pBb, dBb, kt + 1);
        BARRIER();
        mfma16(b0, 4, 0);
        if (kt < 7) { asm volatile("s_waitcnt vmcnt(4)\n\ts_barrier" ::: "memory"); }
        else        { BARRIER(); }
    }

    // ---- epilogue: affine, f32 store, row-sum of exp(s-M), M=|w|+|b| ----
    __syncthreads();   // all LDS reads done before reuse as partials
    const float w = wp[0], bb = bp[0];
    const float M = fabsf(w) + fabsf(bb);
    float* part = (float*)L;   // [4 col-waves][256 rows]
#pragma unroll
    for (int m = 0; m < 8; ++m) {
#pragma unroll
        for (int r = 0; r < 4; ++r) {
            const int rloc = wr * 128 + m * 16 + fhi * 4 + r;
            const size_t grow = (size_t)(brow + rloc);
            float psum = 0.f;
#pragma unroll
            for (int n = 0; n < 4; ++n) {
                const int gcol = bcol + wc * 64 + n * 16 + fr;
                float s = fmaf(w, acc[m][n][r], bb);
                C[grow * B_ROWS + gcol] = s;
                psum += __expf(s - M);
            }
#pragma unroll
            for (int msk = 1; msk <= 8; msk <<= 1) psum += __shfl_xor(psum, msk, 64);
            if (fr == 0) part[wc * 256 + rloc] = psum;
        }
    }
    __syncthreads();
    if (t < 256) {
        float s = part[t] + part[256 + t] + part[512 + t] + part[768 + t];
        rowpart[(size_t)blockIdx.x * B_ROWS + brow + t] = s;
    }
}

// --- Kernel 3: loss = -mean(diag(s) - M - log(rowsum)) ---
__global__ __launch_bounds__(256) void loss_kernel(const float* __restrict__ C,
                                                   const float* __restrict__ rowpart,
                                                   const float* __restrict__ wp,
                                                   const float* __restrict__ bp,
                                                   float* __restrict__ out0) {
    __shared__ float sred[4];
    const int row = blockIdx.x * 256 + threadIdx.x;
    float rs = 0.f;
#pragma unroll
    for (int j = 0; j < 32; ++j) rs += rowpart[(size_t)j * B_ROWS + row];
    const float M = fabsf(wp[0]) + fabsf(bp[0]);
    const float sii = C[(size_t)row * B_ROWS + row];
    float v = sii - M - __logf(rs);
#pragma unroll
    for (int msk = 32; msk >= 1; msk >>= 1) v += __shfl_xor(v, msk, 64);
    if ((threadIdx.x & 63) == 0) sred[threadIdx.x >> 6] = v;
    __syncthreads();
    if (threadIdx.x == 0) {
        float tot = sred[0] + sred[1] + sred[2] + sred[3];
        atomicAdd(out0, -tot / (float)B_ROWS);
    }
}

extern "C" void kernel_launch(void* const* d_in, const int* in_sizes, int n_in,
                              void* d_out, int out_size, void* d_ws, size_t ws_size,
                              hipStream_t stream) {
    const float* A  = (const float*)d_in[1];
    const float* Bf = (const float*)d_in[2];
    const float* wp = (const float*)d_in[3];
    const float* bp = (const float*)d_in[4];
    float* out = (float*)d_out;  // [0] = loss, [1..] = cos_score row-major

    ushort* An = (ushort*)d_ws;
    ushort* Bn = An + (size_t)B_ROWS * DIM;
    float* rowpart = (float*)((char*)d_ws + (size_t)2 * B_ROWS * DIM * sizeof(ushort));

    hipMemsetAsync(d_out, 0, sizeof(float), stream);  // zero the loss slot
    norm_kernel<<<dim3(16384 * 64 / 256), 256, 0, stream>>>(A, Bf, An, Bn);
    dim3 grid(B_ROWS / 256, B_ROWS / 256);
    gemm_kernel<<<grid, 512, 0, stream>>>(An, Bn, out + 1, rowpart, wp, bp);
    loss_kernel<<<B_ROWS / 256, 256, 0, stream>>>(out + 1, rowpart, wp, bp, out);
}